// Round 5
// baseline (220.252 us; speedup 1.0000x reference)
//
#include <hip/hip_runtime.h>

#define N_ 4
#define C_ 256
#define H_ 128
#define W_ 128
#define HW_ (H_*W_)
#define OC 9
#define EPS_ 1e-5f
#define NBLK 512           // grid; co-residency: LDS 81KB -> 2 blk/CU exactly,
                           // 1024 thr -> 2 blk/CU, VGPR<=64 (launch_bounds 8/EU)
                           // -> capacity 2*256 = 512 = grid under any packing.
#define PPB 2              // planes per block

typedef float nfloat4 __attribute__((ext_vector_type(4)));

// Agent-scope relaxed atomics (sc1): bypass non-coherent per-XCD L2, complete
// at L3. No cache-maintenance instructions (R3's 221us was buffer_wbl2 storms).
#define AST(p, v) __hip_atomic_store((p), (v), __ATOMIC_RELAXED, __HIP_MEMORY_SCOPE_AGENT)
#define ALD(p)    __hip_atomic_load((p), __ATOMIC_RELAXED, __HIP_MEMORY_SCOPE_AGENT)

__device__ __forceinline__ void gbar_arrive(unsigned* cnt) {
    __syncthreads();                   // drains this block's sc1 stores (vmcnt0)
    asm volatile("" ::: "memory");
    if (threadIdx.x == 0)
        __hip_atomic_fetch_add(cnt, 1u, __ATOMIC_RELAXED,
                               __HIP_MEMORY_SCOPE_AGENT);
}
__device__ __forceinline__ void gbar_wait(unsigned* cnt) {
    if (threadIdx.x == 0) {
        int bail = 0;
        while (__hip_atomic_load(cnt, __ATOMIC_RELAXED,
                                 __HIP_MEMORY_SCOPE_AGENT) < NBLK) {
            __builtin_amdgcn_s_sleep(2);
            if (++bail > 2000000) break;   // valve: fail clean, never hang
        }
    }
    asm volatile("" ::: "memory");
    __syncthreads();
}

// Staging value for linear chunk vi (row lr = vi/33, chunk k = vi%33).
// Row layout (132 floats): [halo -1][x0..x127][halo 128][2 spare].
// Chunk k holds cols 4k-1..4k+2 -> LDS float idx 4*vi (16B-aligned b128,
// linear across vi => conflict-free ds_write_b128). Global loads are 4B-
// misaligned float4 (legal for global_load_dwordx4), edges composed.
__device__ __forceinline__ float4 stage_val(const float* xin, int vi) {
    int lr = vi / 33;              // magic-mul
    int k  = vi - lr * 33;
    int gr = lr - 1;
    float4 v = make_float4(0.f, 0.f, 0.f, 0.f);
    if (gr >= 0 && gr < H_) {
        const float* row = xin + gr * W_;
        if (k == 0) {
            float4 a; __builtin_memcpy(&a, row, 16);
            v = make_float4(0.f, a.x, a.y, a.z);          // halo | x0 x1 x2
        } else if (k == 32) {
            v = make_float4(row[127], 0.f, 0.f, 0.f);     // x127 | halo | spare
        } else {
            __builtin_memcpy(&v, row + 4 * k - 1, 16);    // cols 4k-1..4k+2
        }
    }
    return v;
}

__device__ __forceinline__ void stage_plane(float* plane_lds, const float* xin,
                                            int t) {
    #pragma unroll
    for (int i = 0; i < 5; ++i) {
        int vi = i * 1024 + t;
        if (vi < 4290) {                           // 130 rows x 33 chunks
            float4 v = stage_val(xin, vi);
            *(float4*)&plane_lds[vi * 4] = v;      // linear, aligned b128
        }
    }
}

// 512 blocks x 1024 threads, 2 blocks/CU (32 waves/CU).
// P1: pool 2 planes -> xpT (sc1).  bar0
// prestage plane pb; blocks 0..8: 4-way-split conv+BN -> w9 (sc1).  bar1
// P3: dwconv plane pb, restage pb+1, dwconv pb+1; nt stores.
__global__ __launch_bounds__(1024, 8) void fused_kernel(
        const float* __restrict__ x, const float* __restrict__ wconv,
        const float* __restrict__ gamma, const float* __restrict__ beta,
        float* __restrict__ xpT, float* __restrict__ w9,
        float* __restrict__ out, unsigned* __restrict__ bar) {
    int b = blockIdx.x;
    int t = threadIdx.x;
    __shared__ __align__(16) float lds[20288];   // 81152 B -> 2 blocks/CU
    float* plane_lds = lds;            // [130*132] = 17160
    float* aux = lds + 17160;          // pool part [2048] / BN red [3072]
    float* ls  = lds + 20232;          // [32]
    float* sc  = lds + 20264;          // [2]
    const int pb = b * PPB;

    // ---------------- Phase 1: pool (2 planes, 512 threads each) ---------
    {
        int g2 = t >> 9, tt = t & 511;     // plane select / thread-in-plane
        int plane = pb + g2;
        const float4* xv = (const float4*)(x + (size_t)plane * HW_);
        int w = tt >> 6, l = tt & 63;
        int j = (l & 31) >> 1;             // col bin 0..15
        bool writer = (l < 32) && ((l & 1) == 0);
        int slot = w & 3, brb = w >> 2;
        float* pp = aux + ((g2 * 4 + slot) << 8);
        #pragma unroll
        for (int k = 0; k < 8; ++k) {
            float4 v = xv[k * 512 + tt];   // coalesced; rows 16k+2w, +1
            float s = v.x + v.y + v.z + v.w;
            s += __shfl_xor(s, 1);         // 8-col chunk of one row
            s += __shfl_xor(s, 32);        // + same cols of row+1
            if (writer) pp[(2 * k + brb) * 16 + j] = s;   // bin-row 2k+brb
        }
        __syncthreads();
        if (t < 512) {                     // reduce 4 row-pair slots per bin
            int g2r = t >> 8, bin = t & 255;
            float* base = aux + (g2r << 10) + bin;
            float r = base[0] + base[256] + base[512] + base[768];
            int plane_id = pb + g2r;
            int n = plane_id >> 8, c = plane_id & 255;
            AST(&xpT[((size_t)c << 10) + (n << 8) + bin], r * (1.f / 64.f));
        }
    }

    gbar_arrive(bar);                      // xpT released (L3)

    stage_plane(plane_lds, x + (size_t)pb * HW_, t);   // overlaps phase 2

    // ---------------- Phase 2: conv+BN on blocks 0..8 (4-way c-split) ----
    if (b < OC) {
        gbar_wait(bar);
        int o = b;
        int q = t & 255, ch = t >> 8;      // sample quad / 64-channel chunk
        const float* wrow = wconv + (o << 8);
        int c0 = ch << 6;
        float ax = 0.f, ay = 0.f, az = 0.f, aw = 0.f;
        #pragma unroll 16
        for (int c = c0; c < c0 + 64; ++c) {
            float wv = wrow[c];
            const float* p = xpT + ((size_t)c << 10) + (q << 2);
            ax += wv * ALD(p);     ay += wv * ALD(p + 1);
            az += wv * ALD(p + 2); aw += wv * ALD(p + 3);
        }
        float* red = aux;                  // [3][256][4]
        if (ch) {
            float* r = red + ((ch - 1) << 10) + (q << 2);
            r[0] = ax; r[1] = ay; r[2] = az; r[3] = aw;
        }
        __syncthreads();
        if (ch == 0) {
            int q4 = q << 2;
            ax += red[q4]     + red[1024 + q4]     + red[2048 + q4];
            ay += red[q4 + 1] + red[1024 + q4 + 1] + red[2048 + q4 + 1];
            az += red[q4 + 2] + red[1024 + q4 + 2] + red[2048 + q4 + 2];
            aw += red[q4 + 3] + red[1024 + q4 + 3] + red[2048 + q4 + 3];
            float sum = ax + ay + az + aw;
            float sq  = ax*ax + ay*ay + az*az + aw*aw;
            #pragma unroll
            for (int off = 32; off > 0; off >>= 1) {
                sum += __shfl_down(sum, off);
                sq  += __shfl_down(sq,  off);
            }
            if ((q & 63) == 0) { ls[q >> 6] = sum; ls[16 + (q >> 6)] = sq; }
        }
        __syncthreads();
        if (t == 0) {
            float S = ls[0] + ls[1] + ls[2] + ls[3];
            float Q = ls[16] + ls[17] + ls[18] + ls[19];
            float mu = S * (1.f / 1024.f);
            float var = Q * (1.f / 1024.f) - mu * mu;
            float scale = gamma[o] * rsqrtf(var + EPS_);
            sc[0] = scale;
            sc[1] = beta[o] - mu * scale;
        }
        __syncthreads();
        if (ch == 0) {
            float scale = sc[0], shift = sc[1];
            int s0 = q << 2;
            AST(&w9[(s0 + 0) * 9 + o], ax * scale + shift);
            AST(&w9[(s0 + 1) * 9 + o], ay * scale + shift);
            AST(&w9[(s0 + 2) * 9 + o], az * scale + shift);
            AST(&w9[(s0 + 3) * 9 + o], aw * scale + shift);
        }
    }

    gbar_arrive(bar + 1);                  // w9 released
    gbar_wait(bar + 1);

    // ---------------- Phase 3: depthwise 3x3, 2 planes ----------
    int mr = t >> 5, mc = t & 31;          // 4x4 micro-tile per thread
    int olr = mr * 4, oc0 = mc * 4;
    #pragma unroll 1
    for (int g = 0; g < PPB; ++g) {
        int plane = pb + g;
        float w[9];                        // per-plane taps (uniform per block)
        #pragma unroll
        for (int i = 0; i < 9; ++i) w[i] = ALD(&w9[plane * 9 + i]);
        float rowv[6][6];                  // rows olr-1..olr+4, cols oc0-1..+4
        #pragma unroll
        for (int j = 0; j < 6; ++j) {
            const float* rp = &plane_lds[(olr + j) * 132 + oc0];
            float4 a  = *(const float4*)rp;        // cols oc0-1..oc0+2
            float4 bq = *(const float4*)(rp + 4);  // cols oc0+3..+6 (use 2)
            rowv[j][0] = a.x;  rowv[j][1] = a.y;
            rowv[j][2] = a.z;  rowv[j][3] = a.w;
            rowv[j][4] = bq.x; rowv[j][5] = bq.y;
        }
        float* po = out + (size_t)plane * HW_;
        #pragma unroll
        for (int rr = 0; rr < 4; ++rr) {
            float res[4];
            #pragma unroll
            for (int cc = 0; cc < 4; ++cc) {
                float s = 0.f;
                #pragma unroll
                for (int dy = 0; dy < 3; ++dy)
                    #pragma unroll
                    for (int dx = 0; dx < 3; ++dx)
                        s += w[dy * 3 + dx] * rowv[rr + dy][cc + dx];
                res[cc] = s;
            }
            nfloat4 rv = { res[0], res[1], res[2], res[3] };
            __builtin_nontemporal_store(rv,
                (nfloat4*)&po[(olr + rr) * W_ + oc0]);
        }
        if (g < PPB - 1) {                 // restage next plane (x is L3-hot)
            __syncthreads();
            stage_plane(plane_lds, x + (size_t)(plane + 1) * HW_, t);
            __syncthreads();
        }
    }
}

extern "C" void kernel_launch(void* const* d_in, const int* in_sizes, int n_in,
                              void* d_out, int out_size, void* d_ws, size_t ws_size,
                              hipStream_t stream) {
    const float* x     = (const float*)d_in[0];
    const float* wconv = (const float*)d_in[1];
    const float* gamma = (const float*)d_in[2];
    const float* beta  = (const float*)d_in[3];
    float* out = (float*)d_out;

    float* xpT = (float*)d_ws;                   // C*N*256 = 262144 floats
    float* w9  = xpT + C_ * N_ * 256;            // N*256*OC = 9216 floats
    unsigned* bar = (unsigned*)(w9 + N_ * 256 * OC);   // 2 counters

    hipMemsetAsync(bar, 0, 2 * sizeof(unsigned), stream);  // ws is poisoned
    hipLaunchKernelGGL(fused_kernel, dim3(NBLK), dim3(1024), 0, stream,
                       x, wconv, gamma, beta, xpT, w9, out, bar);
}

// Round 7
// 215.210 us; speedup vs baseline: 1.0234x; 1.0234x over previous
//
#include <hip/hip_runtime.h>

#define N_ 4
#define C_ 256
#define H_ 128
#define W_ 128
#define HW_ (H_*W_)
#define OC 9
#define EPS_ 1e-5f
#define NBLK 256           // 1 block/CU (LDS 146KB) -> all 256 co-resident
#define PPB 4              // planes per block

typedef float nfloat4 __attribute__((ext_vector_type(4)));

// Agent-scope relaxed atomics (sc1): bypass non-coherent per-XCD L2, complete
// at L3. No cache-maintenance instructions (R3's 221us was buffer_wbl2 storms).
#define AST(p, v) __hip_atomic_store((p), (v), __ATOMIC_RELAXED, __HIP_MEMORY_SCOPE_AGENT)
#define ALD(p)    __hip_atomic_load((p), __ATOMIC_RELAXED, __HIP_MEMORY_SCOPE_AGENT)

__device__ __forceinline__ void gbar_arrive(unsigned* cnt) {
    __syncthreads();                   // drains this block's sc1 stores
    asm volatile("" ::: "memory");
    if (threadIdx.x == 0)
        __hip_atomic_fetch_add(cnt, 1u, __ATOMIC_RELAXED,
                               __HIP_MEMORY_SCOPE_AGENT);
}
__device__ __forceinline__ void gbar_wait(unsigned* cnt) {
    if (threadIdx.x == 0) {
        int bail = 0;
        while (__hip_atomic_load(cnt, __ATOMIC_RELAXED,
                                 __HIP_MEMORY_SCOPE_AGENT) < NBLK) {
            __builtin_amdgcn_s_sleep(2);
            if (++bail > 2000000) break;   // valve: fail clean, never hang
        }
    }
    asm volatile("" ::: "memory");
    __syncthreads();
}

// 256 blocks x 1024 threads, 1 block/CU.
// Plane buffers: [130][128] floats, rows 1..128 = x rows 0..127 (LINEAR copy,
// aligned b128 both sides); rows 0,129 zeroed once. No column halo in LDS:
// col -1 / col +4 are read as clamped scalar LDS loads + select (NO shfl --
// R6's guarded shfl read from exec-disabled lanes = undefined data).
__global__ __launch_bounds__(1024) void fused_kernel(
        const float* __restrict__ x, const float* __restrict__ wconv,
        const float* __restrict__ gamma, const float* __restrict__ beta,
        float* __restrict__ xpT, float* __restrict__ w9,
        float* __restrict__ out, unsigned* __restrict__ bar) {
    int b = blockIdx.x;
    int t = threadIdx.x;
    __shared__ __align__(16) float bufA[130 * 128];   // 66560 B
    __shared__ __align__(16) float bufB[130 * 128];   // 66560 B
    __shared__ __align__(16) float aux[4096];         // pool partials / BN red
    __shared__ float ls[32];
    __shared__ float sc[2];
    const int pb = b * PPB;

    // zero halo rows (rows 0 and 129 of both buffers) -- stays zero forever
    if (t < 128) {
        bufA[t] = 0.f;              bufB[t] = 0.f;
        bufA[129 * 128 + t] = 0.f;  bufB[129 * 128 + t] = 0.f;
    }

    // -------- Phase 1: pool 4 planes; groups 0,1 tee loads into bufA/B ----
    {
        int g = t >> 8, tt = t & 255;      // plane group / thread-in-group
        int plane = pb + g;
        int n = plane >> 8, c = plane & 255;
        const float4* xv = (const float4*)(x + (size_t)plane * HW_);
        float* part = aux + (g << 10);
        float* sbuf = (g == 0) ? bufA : bufB;     // used only when g < 2
        int w = tt >> 6, l = tt & 63;
        int j = (l & 31) >> 1;             // col bin 0..15
        bool writer = (l < 32) && ((l & 1) == 0);
        #pragma unroll
        for (int k = 0; k < 16; ++k) {
            float4 v = xv[k * 256 + tt];   // coalesced
            if (g < 2)                     // stage planes 0,1 for free
                *(float4*)&sbuf[128 + (((k << 8) + tt) << 2)] = v;
            float s = v.x + v.y + v.z + v.w;
            s += __shfl_xor(s, 1);         // pair lanes -> 8-col chunk of row
            s += __shfl_xor(s, 32);        // + same cols of row+1
            if (writer) part[w * 256 + k * 16 + j] = s;
        }
        __syncthreads();
        float r = part[tt] + part[256 + tt] + part[512 + tt] + part[768 + tt];
        AST(&xpT[((size_t)c << 10) + (n << 8) + tt], r * (1.f / 64.f));
    }

    gbar_arrive(bar);                      // xpT released (L3)

    // -------- Phase 2: conv+BN on blocks 0..8 (4-way c-split) -------------
    if (b < OC) {
        gbar_wait(bar);
        int o = b;
        int q = t & 255, ch = t >> 8;      // sample quad / 64-channel chunk
        const float* wrow = wconv + (o << 8);
        int c0 = ch << 6;
        float ax = 0.f, ay = 0.f, az = 0.f, aw = 0.f;
        #pragma unroll 16
        for (int c = c0; c < c0 + 64; ++c) {
            float wv = wrow[c];
            const float* p = xpT + ((size_t)c << 10) + (q << 2);
            ax += wv * ALD(p);     ay += wv * ALD(p + 1);
            az += wv * ALD(p + 2); aw += wv * ALD(p + 3);
        }
        float* red = aux;                  // [3][256][4]
        if (ch) {
            float4 rv = { ax, ay, az, aw };
            *(float4*)&red[((ch - 1) << 10) + (q << 2)] = rv;
        }
        __syncthreads();
        if (ch == 0) {
            float4 r0v = *(const float4*)&red[(q << 2)];
            float4 r1v = *(const float4*)&red[1024 + (q << 2)];
            float4 r2v = *(const float4*)&red[2048 + (q << 2)];
            ax += r0v.x + r1v.x + r2v.x;
            ay += r0v.y + r1v.y + r2v.y;
            az += r0v.z + r1v.z + r2v.z;
            aw += r0v.w + r1v.w + r2v.w;
            float sum = ax + ay + az + aw;
            float sq  = ax*ax + ay*ay + az*az + aw*aw;
            #pragma unroll
            for (int off = 32; off > 0; off >>= 1) {
                sum += __shfl_down(sum, off);
                sq  += __shfl_down(sq,  off);
            }
            if ((q & 63) == 0) { ls[q >> 6] = sum; ls[16 + (q >> 6)] = sq; }
        }
        __syncthreads();
        if (t == 0) {
            float S = ls[0] + ls[1] + ls[2] + ls[3];
            float Q = ls[16] + ls[17] + ls[18] + ls[19];
            float mu = S * (1.f / 1024.f);
            float var = Q * (1.f / 1024.f) - mu * mu;
            float scale = gamma[o] * rsqrtf(var + EPS_);
            sc[0] = scale;
            sc[1] = beta[o] - mu * scale;
        }
        __syncthreads();
        if (ch == 0) {
            float scale = sc[0], shift = sc[1];
            int s0 = q << 2;
            AST(&w9[(s0 + 0) * 9 + o], ax * scale + shift);
            AST(&w9[(s0 + 1) * 9 + o], ay * scale + shift);
            AST(&w9[(s0 + 2) * 9 + o], az * scale + shift);
            AST(&w9[(s0 + 3) * 9 + o], aw * scale + shift);
        }
    }

    gbar_arrive(bar + 1);                  // w9 released
    gbar_wait(bar + 1);

    // -------- Phase 3: depthwise 3x3, double-buffered planes --------------
    int mr = t >> 5, mc = t & 31;          // 4x4 micro-tile per thread
    int r0 = mr * 4, oc0 = mc * 4;         // out rows r0..r0+3, cols oc0..+3
    float4 pre[4];
    #pragma unroll
    for (int g = 0; g < PPB; ++g) {
        float* buf = (g & 1) ? bufB : bufA;
        int plane = pb + g;
        if (g < 2) {                       // prefetch plane g+2 (linear copy)
            const float* xn = x + (size_t)(pb + g + 2) * HW_;
            #pragma unroll
            for (int i = 0; i < 4; ++i)
                pre[i] = *(const float4*)&xn[(i * 1024 + t) << 2];
        }
        float w[9];                        // block-uniform taps
        #pragma unroll
        for (int i = 0; i < 9; ++i) w[i] = ALD(&w9[plane * 9 + i]);
        // 6 aligned b128 reads (rows r0..r0+5 = x rows r0-1..r0+4);
        // halo cols via clamped scalar LDS reads + select (divergence-safe)
        float rc[6][4], rl[6], rrr[6];
        int lcl = (mc == 0)  ? 0   : (oc0 - 1);    // clamped, in-bounds
        int rcl = (mc == 31) ? 127 : (oc0 + 4);
        #pragma unroll
        for (int j = 0; j < 6; ++j) {
            const float* rp = &buf[(r0 + j) * 128];
            float4 q = *(const float4*)&rp[oc0];
            float lv = rp[lcl];
            float rv = rp[rcl];
            rl[j]  = (mc == 0)  ? 0.f : lv;        // x col oc0-1 (or pad 0)
            rrr[j] = (mc == 31) ? 0.f : rv;        // x col oc0+4 (or pad 0)
            rc[j][0] = q.x; rc[j][1] = q.y; rc[j][2] = q.z; rc[j][3] = q.w;
        }
        float* po = out + (size_t)plane * HW_;
        #pragma unroll
        for (int rr = 0; rr < 4; ++rr) {
            float res[4];
            #pragma unroll
            for (int cc = 0; cc < 4; ++cc) {
                float s = 0.f;
                #pragma unroll
                for (int dy = 0; dy < 3; ++dy) {
                    #pragma unroll
                    for (int dx = 0; dx < 3; ++dx) {
                        int col = cc + dx - 1;              // compile-time
                        float vv = (col < 0) ? rl[rr + dy]
                                 : (col > 3) ? rrr[rr + dy]
                                 : rc[rr + dy][col];
                        s += w[dy * 3 + dx] * vv;
                    }
                }
                res[cc] = s;
            }
            nfloat4 rv = { res[0], res[1], res[2], res[3] };
            __builtin_nontemporal_store(rv,
                (nfloat4*)&po[(r0 + rr) * W_ + oc0]);
        }
        if (g < PPB - 1) {
            __syncthreads();               // all reads of buf done block-wide
            if (g < 2) {                   // write plane g+2 into same buf
                #pragma unroll
                for (int i = 0; i < 4; ++i)
                    *(float4*)&buf[128 + ((i * 1024 + t) << 2)] = pre[i];
            }
        }
    }
}

extern "C" void kernel_launch(void* const* d_in, const int* in_sizes, int n_in,
                              void* d_out, int out_size, void* d_ws, size_t ws_size,
                              hipStream_t stream) {
    const float* x     = (const float*)d_in[0];
    const float* wconv = (const float*)d_in[1];
    const float* gamma = (const float*)d_in[2];
    const float* beta  = (const float*)d_in[3];
    float* out = (float*)d_out;

    float* xpT = (float*)d_ws;                   // C*N*256 = 262144 floats
    float* w9  = xpT + C_ * N_ * 256;            // N*256*OC = 9216 floats
    unsigned* bar = (unsigned*)(w9 + N_ * 256 * OC);   // 2 counters

    hipMemsetAsync(bar, 0, 2 * sizeof(unsigned), stream);  // ws is poisoned
    hipLaunchKernelGGL(fused_kernel, dim3(NBLK), dim3(1024), 0, stream,
                       x, wconv, gamma, beta, xpT, w9, out, bar);
}

// Round 8
// 197.784 us; speedup vs baseline: 1.1136x; 1.0881x over previous
//
#include <hip/hip_runtime.h>

#define N_ 4
#define C_ 256
#define H_ 128
#define W_ 128
#define HW_ (H_*W_)
#define OC 9
#define EPS_ 1e-5f
#define NBLK 256           // 1 block/CU (LDS 146KB) -> all 256 co-resident
#define PPB 4              // planes per block

typedef float nfloat4 __attribute__((ext_vector_type(4)));

// Agent-scope relaxed atomics (sc1): bypass non-coherent per-XCD L2, complete
// at L3. No cache-maintenance instructions (R3's 221us was buffer_wbl2 storms).
#define AST(p, v) __hip_atomic_store((p), (v), __ATOMIC_RELAXED, __HIP_MEMORY_SCOPE_AGENT)
#define ALD(p)    __hip_atomic_load((p), __ATOMIC_RELAXED, __HIP_MEMORY_SCOPE_AGENT)

__device__ __forceinline__ void gbar_arrive(unsigned* cnt) {
    __syncthreads();                   // drains this block's sc1 stores
    asm volatile("" ::: "memory");
    if (threadIdx.x == 0)
        __hip_atomic_fetch_add(cnt, 1u, __ATOMIC_RELAXED,
                               __HIP_MEMORY_SCOPE_AGENT);
}
__device__ __forceinline__ void gbar_wait(unsigned* cnt) {
    if (threadIdx.x == 0) {
        int bail = 0;
        while (__hip_atomic_load(cnt, __ATOMIC_RELAXED,
                                 __HIP_MEMORY_SCOPE_AGENT) < NBLK) {
            __builtin_amdgcn_s_sleep(2);
            if (++bail > 2000000) break;   // valve: fail clean, never hang
        }
    }
    asm volatile("" ::: "memory");
    __syncthreads();
}

// Async DMA stage of one full plane (64KB, rows 1..128 of lbuf) via
// global_load_lds width=16: LDS dest = wave-uniform base + lane*16 (linear
// layout, no column halo -> exactly matches the DMA pattern). No VGPRs used;
// completion via vmcnt drain at the next __syncthreads.
__device__ __forceinline__ void stage_async(float* lbuf, const float* xn,
                                            int t) {
    int wv = t >> 6, lane = t & 63;
    #pragma unroll
    for (int i = 0; i < 4; ++i) {
        int chunk = (wv << 2) + i;                     // 64 x 1KB chunks
        const float* gp = xn + (chunk << 8) + (lane << 2);   // per-lane src
        float* lp = lbuf + 128 + (chunk << 8);         // wave-uniform dest
        __builtin_amdgcn_global_load_lds(
            (const __attribute__((address_space(1))) void*)(unsigned long long)gp,
            (__attribute__((address_space(3))) void*)lp,
            16, 0, 0);
    }
}

// 256 blocks x 1024 threads, 1 block/CU.
// Plane buffers: [130][128] floats, rows 1..128 = x rows 0..127 (LINEAR copy);
// rows 0,129 zeroed once. Col halos: clamped scalar LDS reads + select
// (divergence-safe; R6's guarded shfl was UB and corrupted halo taps).
__global__ __launch_bounds__(1024, 4) void fused_kernel(
        const float* __restrict__ x, const float* __restrict__ wconv,
        const float* __restrict__ gamma, const float* __restrict__ beta,
        float* __restrict__ xpT, float* __restrict__ w9,
        float* __restrict__ out, unsigned* __restrict__ bar) {
    int b = blockIdx.x;
    int t = threadIdx.x;
    __shared__ __align__(16) float bufA[130 * 128];   // 66560 B
    __shared__ __align__(16) float bufB[130 * 128];   // 66560 B
    __shared__ __align__(16) float aux[4096];         // pool partials / BN red
    __shared__ float ls[32];
    __shared__ float sc[2];
    const int pb = b * PPB;

    // zero halo rows (rows 0 and 129 of both buffers) -- stays zero forever
    if (t < 128) {
        bufA[t] = 0.f;              bufB[t] = 0.f;
        bufA[129 * 128 + t] = 0.f;  bufB[129 * 128 + t] = 0.f;
    }

    // -------- Phase 1: pool 4 planes; groups 0,1 tee loads into bufA/B ----
    {
        int g = t >> 8, tt = t & 255;      // plane group / thread-in-group
        int plane = pb + g;
        int n = plane >> 8, c = plane & 255;
        const float4* xv = (const float4*)(x + (size_t)plane * HW_);
        float* part = aux + (g << 10);
        float* sbuf = (g == 0) ? bufA : bufB;     // used only when g < 2
        int w = tt >> 6, l = tt & 63;
        int j = (l & 31) >> 1;             // col bin 0..15
        bool writer = (l < 32) && ((l & 1) == 0);
        #pragma unroll
        for (int k = 0; k < 16; ++k) {
            float4 v = xv[k * 256 + tt];   // coalesced
            if (g < 2)                     // stage planes 0,1 for free
                *(float4*)&sbuf[128 + (((k << 8) + tt) << 2)] = v;
            float s = v.x + v.y + v.z + v.w;
            s += __shfl_xor(s, 1);         // pair lanes -> 8-col chunk of row
            s += __shfl_xor(s, 32);        // + same cols of row+1
            if (writer) part[w * 256 + k * 16 + j] = s;
        }
        __syncthreads();
        float r = part[tt] + part[256 + tt] + part[512 + tt] + part[768 + tt];
        AST(&xpT[((size_t)c << 10) + (n << 8) + tt], r * (1.f / 64.f));
    }

    gbar_arrive(bar);                      // xpT released (L3)

    // -------- Phase 2: conv+BN on blocks 0..8 (4-way c-split) -------------
    if (b < OC) {
        gbar_wait(bar);
        int o = b;
        int q = t & 255, ch = t >> 8;      // sample quad / 64-channel chunk
        const float* wrow = wconv + (o << 8);
        int c0 = ch << 6;
        float ax = 0.f, ay = 0.f, az = 0.f, aw = 0.f;
        #pragma unroll 16
        for (int c = c0; c < c0 + 64; ++c) {
            float wv = wrow[c];
            const float* p = xpT + ((size_t)c << 10) + (q << 2);
            ax += wv * ALD(p);     ay += wv * ALD(p + 1);
            az += wv * ALD(p + 2); aw += wv * ALD(p + 3);
        }
        float* red = aux;                  // [3][256][4]
        if (ch) {
            float4 rv = { ax, ay, az, aw };
            *(float4*)&red[((ch - 1) << 10) + (q << 2)] = rv;
        }
        __syncthreads();
        if (ch == 0) {
            float4 r0v = *(const float4*)&red[(q << 2)];
            float4 r1v = *(const float4*)&red[1024 + (q << 2)];
            float4 r2v = *(const float4*)&red[2048 + (q << 2)];
            ax += r0v.x + r1v.x + r2v.x;
            ay += r0v.y + r1v.y + r2v.y;
            az += r0v.z + r1v.z + r2v.z;
            aw += r0v.w + r1v.w + r2v.w;
            float sum = ax + ay + az + aw;
            float sq  = ax*ax + ay*ay + az*az + aw*aw;
            #pragma unroll
            for (int off = 32; off > 0; off >>= 1) {
                sum += __shfl_down(sum, off);
                sq  += __shfl_down(sq,  off);
            }
            if ((q & 63) == 0) { ls[q >> 6] = sum; ls[16 + (q >> 6)] = sq; }
        }
        __syncthreads();
        if (t == 0) {
            float S = ls[0] + ls[1] + ls[2] + ls[3];
            float Q = ls[16] + ls[17] + ls[18] + ls[19];
            float mu = S * (1.f / 1024.f);
            float var = Q * (1.f / 1024.f) - mu * mu;
            float scale = gamma[o] * rsqrtf(var + EPS_);
            sc[0] = scale;
            sc[1] = beta[o] - mu * scale;
        }
        __syncthreads();
        if (ch == 0) {
            float scale = sc[0], shift = sc[1];
            int s0 = q << 2;
            AST(&w9[(s0 + 0) * 9 + o], ax * scale + shift);
            AST(&w9[(s0 + 1) * 9 + o], ay * scale + shift);
            AST(&w9[(s0 + 2) * 9 + o], az * scale + shift);
            AST(&w9[(s0 + 3) * 9 + o], aw * scale + shift);
        }
    }

    gbar_arrive(bar + 1);                  // w9 released
    gbar_wait(bar + 1);

    // -------- Phase 3: depthwise 3x3, DMA double-buffered planes ----------
    // p0/p1 already resident (pool tee). Schedule:
    //   g=0: compute A(p0); sync; DMA p2->A (flies under g=1)
    //   g=1: compute B(p1); sync(vmcnt0: p2 landed); DMA p3->B
    //   g=2: compute A(p2); sync(p3 landed)
    //   g=3: compute B(p3)
    int mr = t >> 5, mc = t & 31;          // 4x4 micro-tile per thread
    int r0 = mr * 4, oc0 = mc * 4;         // out rows r0..r0+3, cols oc0..+3
    #pragma unroll
    for (int g = 0; g < PPB; ++g) {
        float* buf = (g & 1) ? bufB : bufA;
        int plane = pb + g;
        float w[9];                        // block-uniform taps
        #pragma unroll
        for (int i = 0; i < 9; ++i) w[i] = ALD(&w9[plane * 9 + i]);
        // 6 aligned b128 reads (rows r0..r0+5 = x rows r0-1..r0+4);
        // halo cols via clamped scalar LDS reads + select (divergence-safe)
        float rc[6][4], rl[6], rrr[6];
        int lcl = (mc == 0)  ? 0   : (oc0 - 1);    // clamped, in-bounds
        int rcl = (mc == 31) ? 127 : (oc0 + 4);
        #pragma unroll
        for (int j = 0; j < 6; ++j) {
            const float* rp = &buf[(r0 + j) * 128];
            float4 q = *(const float4*)&rp[oc0];
            float lv = rp[lcl];
            float rv = rp[rcl];
            rl[j]  = (mc == 0)  ? 0.f : lv;        // x col oc0-1 (or pad 0)
            rrr[j] = (mc == 31) ? 0.f : rv;        // x col oc0+4 (or pad 0)
            rc[j][0] = q.x; rc[j][1] = q.y; rc[j][2] = q.z; rc[j][3] = q.w;
        }
        float* po = out + (size_t)plane * HW_;
        #pragma unroll
        for (int rr = 0; rr < 4; ++rr) {
            float res[4];
            #pragma unroll
            for (int cc = 0; cc < 4; ++cc) {
                float s = 0.f;
                #pragma unroll
                for (int dy = 0; dy < 3; ++dy) {
                    #pragma unroll
                    for (int dx = 0; dx < 3; ++dx) {
                        int col = cc + dx - 1;              // compile-time
                        float vv = (col < 0) ? rl[rr + dy]
                                 : (col > 3) ? rrr[rr + dy]
                                 : rc[rr + dy][col];
                        s += w[dy * 3 + dx] * vv;
                    }
                }
                res[cc] = s;
            }
            nfloat4 rv = { res[0], res[1], res[2], res[3] };
            __builtin_nontemporal_store(rv,
                (nfloat4*)&po[(r0 + rr) * W_ + oc0]);
        }
        if (g < PPB - 1) {
            // drain pending DMA into the OTHER buffer + finish reads of buf
            asm volatile("s_waitcnt vmcnt(0)" ::: "memory");
            __syncthreads();
            if (g < 2)                     // DMA plane g+2 into freed buf
                stage_async(buf, x + (size_t)(pb + g + 2) * HW_, t);
        }
    }
}

extern "C" void kernel_launch(void* const* d_in, const int* in_sizes, int n_in,
                              void* d_out, int out_size, void* d_ws, size_t ws_size,
                              hipStream_t stream) {
    const float* x     = (const float*)d_in[0];
    const float* wconv = (const float*)d_in[1];
    const float* gamma = (const float*)d_in[2];
    const float* beta  = (const float*)d_in[3];
    float* out = (float*)d_out;

    float* xpT = (float*)d_ws;                   // C*N*256 = 262144 floats
    float* w9  = xpT + C_ * N_ * 256;            // N*256*OC = 9216 floats
    unsigned* bar = (unsigned*)(w9 + N_ * 256 * OC);   // 2 counters

    hipMemsetAsync(bar, 0, 2 * sizeof(unsigned), stream);  // ws is poisoned
    hipLaunchKernelGGL(fused_kernel, dim3(NBLK), dim3(1024), 0, stream,
                       x, wconv, gamma, beta, xpT, w9, out, bar);
}

// Round 9
// 195.293 us; speedup vs baseline: 1.1278x; 1.0128x over previous
//
#include <hip/hip_runtime.h>

#define N_ 4
#define C_ 256
#define H_ 128
#define W_ 128
#define HW_ (H_*W_)
#define OC 9
#define EPS_ 1e-5f
#define NBLK 256           // 1 block/CU (LDS 83KB) -> all 256 co-resident
#define PPB 4              // planes per block

typedef float nfloat4 __attribute__((ext_vector_type(4)));

// Agent-scope relaxed atomics (sc1): bypass non-coherent per-XCD L2, complete
// at L3. No cache-maintenance instructions (R3's 221us was buffer_wbl2 storms).
#define AST(p, v) __hip_atomic_store((p), (v), __ATOMIC_RELAXED, __HIP_MEMORY_SCOPE_AGENT)
#define ALD(p)    __hip_atomic_load((p), __ATOMIC_RELAXED, __HIP_MEMORY_SCOPE_AGENT)

__device__ __forceinline__ void gbar_arrive(unsigned* cnt) {
    __syncthreads();                   // drains this block's sc1 stores
    asm volatile("" ::: "memory");
    if (threadIdx.x == 0)
        __hip_atomic_fetch_add(cnt, 1u, __ATOMIC_RELAXED,
                               __HIP_MEMORY_SCOPE_AGENT);
}
__device__ __forceinline__ void gbar_wait(unsigned* cnt) {
    if (threadIdx.x == 0) {
        int bail = 0;
        while (__hip_atomic_load(cnt, __ATOMIC_RELAXED,
                                 __HIP_MEMORY_SCOPE_AGENT) < NBLK) {
            __builtin_amdgcn_s_sleep(2);
            if (++bail > 2000000) break;   // valve: fail clean, never hang
        }
    }
    asm volatile("" ::: "memory");
    __syncthreads();
}

// Linear stage: x rows 0..127 -> buf rows 1..128 (cols direct). Aligned b128
// both sides, conflict-free (R4's +1-shifted layout forced 4x ds_write_b32
// at 16B lane stride = 8-way bank conflicts).
__device__ __forceinline__ void stage_linear(float* buf, const float* xin,
                                             int t) {
    #pragma unroll
    for (int i = 0; i < 4; ++i) {
        int vi = i * 1024 + t;                     // 0..4095
        *(float4*)&buf[128 + (vi << 2)] = *(const float4*)&xin[vi << 2];
    }
}

// 256 blocks x 1024 threads, 1 block/CU. R4's proven schedule, new layout:
// plane buffer [130][128]; rows 0,129 zeroed once; col halos via clamped
// scalar LDS reads + select (divergence-safe, R8-refcheck-proven).
__global__ __launch_bounds__(1024, 4) void fused_kernel(
        const float* __restrict__ x, const float* __restrict__ wconv,
        const float* __restrict__ gamma, const float* __restrict__ beta,
        float* __restrict__ xpT, float* __restrict__ w9,
        float* __restrict__ out, unsigned* __restrict__ bar) {
    int b = blockIdx.x;
    int t = threadIdx.x;
    __shared__ __align__(16) float buf[130 * 128];    // 66560 B
    __shared__ __align__(16) float aux[4096];         // pool partials / BN red
    __shared__ float ls[32];
    __shared__ float sc[2];
    const int pb = b * PPB;

    // zero halo rows (rows 0 and 129) -- never rewritten
    if (t < 128) { buf[t] = 0.f; buf[129 * 128 + t] = 0.f; }

    // -------- Phase 1: pool 4 planes (1 per 256-thread group) -------------
    {
        int g = t >> 8, tt = t & 255;      // plane group / thread-in-group
        int plane = pb + g;
        int n = plane >> 8, c = plane & 255;
        const float4* xv = (const float4*)(x + (size_t)plane * HW_);
        float* part = aux + (g << 10);
        int w = tt >> 6, l = tt & 63;
        int j = (l & 31) >> 1;             // col bin 0..15
        bool writer = (l < 32) && ((l & 1) == 0);
        #pragma unroll
        for (int k = 0; k < 16; ++k) {
            float4 v = xv[k * 256 + tt];   // coalesced
            float s = v.x + v.y + v.z + v.w;
            s += __shfl_xor(s, 1);         // pair lanes -> 8-col chunk of row
            s += __shfl_xor(s, 32);        // + same cols of row+1
            if (writer) part[w * 256 + k * 16 + j] = s;
        }
        __syncthreads();
        float r = part[tt] + part[256 + tt] + part[512 + tt] + part[768 + tt];
        AST(&xpT[((size_t)c << 10) + (n << 8) + tt], r * (1.f / 64.f));
    }

    gbar_arrive(bar);                      // xpT released (L3)

    stage_linear(buf, x + (size_t)pb * HW_, t);   // p0; overlaps skew+phase2

    // -------- Phase 2: conv+BN on blocks 0..8 (4-way c-split) -------------
    if (b < OC) {
        gbar_wait(bar);
        int o = b;
        int q = t & 255, ch = t >> 8;      // sample quad / 64-channel chunk
        const float* wrow = wconv + (o << 8);
        int c0 = ch << 6;
        float ax = 0.f, ay = 0.f, az = 0.f, aw = 0.f;
        #pragma unroll 16
        for (int c = c0; c < c0 + 64; ++c) {
            float wv = wrow[c];
            const float* p = xpT + ((size_t)c << 10) + (q << 2);
            ax += wv * ALD(p);     ay += wv * ALD(p + 1);
            az += wv * ALD(p + 2); aw += wv * ALD(p + 3);
        }
        float* red = aux;                  // [3][256][4]
        if (ch) {
            float4 rv = { ax, ay, az, aw };
            *(float4*)&red[((ch - 1) << 10) + (q << 2)] = rv;
        }
        __syncthreads();
        if (ch == 0) {
            float4 r0v = *(const float4*)&red[(q << 2)];
            float4 r1v = *(const float4*)&red[1024 + (q << 2)];
            float4 r2v = *(const float4*)&red[2048 + (q << 2)];
            ax += r0v.x + r1v.x + r2v.x;
            ay += r0v.y + r1v.y + r2v.y;
            az += r0v.z + r1v.z + r2v.z;
            aw += r0v.w + r1v.w + r2v.w;
            float sum = ax + ay + az + aw;
            float sq  = ax*ax + ay*ay + az*az + aw*aw;
            #pragma unroll
            for (int off = 32; off > 0; off >>= 1) {
                sum += __shfl_down(sum, off);
                sq  += __shfl_down(sq,  off);
            }
            if ((q & 63) == 0) { ls[q >> 6] = sum; ls[16 + (q >> 6)] = sq; }
        }
        __syncthreads();
        if (t == 0) {
            float S = ls[0] + ls[1] + ls[2] + ls[3];
            float Q = ls[16] + ls[17] + ls[18] + ls[19];
            float mu = S * (1.f / 1024.f);
            float var = Q * (1.f / 1024.f) - mu * mu;
            float scale = gamma[o] * rsqrtf(var + EPS_);
            sc[0] = scale;
            sc[1] = beta[o] - mu * scale;
        }
        __syncthreads();
        if (ch == 0) {
            float scale = sc[0], shift = sc[1];
            int s0 = q << 2;
            AST(&w9[(s0 + 0) * 9 + o], ax * scale + shift);
            AST(&w9[(s0 + 1) * 9 + o], ay * scale + shift);
            AST(&w9[(s0 + 2) * 9 + o], az * scale + shift);
            AST(&w9[(s0 + 3) * 9 + o], aw * scale + shift);
        }
    }

    gbar_arrive(bar + 1);                  // w9 released

    // prefetch plane pb+1 into regs: in flight during bar1 spin
    float4 pre[4];
    {
        const float* xn = x + (size_t)(pb + 1) * HW_;
        #pragma unroll
        for (int i = 0; i < 4; ++i)
            pre[i] = *(const float4*)&xn[(i * 1024 + t) << 2];
    }

    gbar_wait(bar + 1);                    // w9 visible

    // -------- Phase 3: depthwise 3x3, reg-pipelined single buffer ---------
    int mr = t >> 5, mc = t & 31;          // 4x4 micro-tile per thread
    int r0 = mr * 4, oc0 = mc * 4;         // out rows r0..r0+3, cols oc0..+3
    int lcl = (mc == 0)  ? 0   : (oc0 - 1);    // clamped, in-bounds
    int rcl = (mc == 31) ? 127 : (oc0 + 4);
    #pragma unroll 1
    for (int g = 0; g < PPB; ++g) {
        int plane = pb + g;
        float w[9];                        // block-uniform taps
        #pragma unroll
        for (int i = 0; i < 9; ++i) w[i] = ALD(&w9[plane * 9 + i]);
        // 6 aligned b128 reads (buf rows r0..r0+5 = x rows r0-1..r0+4);
        // halo cols via clamped scalar LDS reads + select
        float rc[6][4], rl[6], rrr[6];
        #pragma unroll
        for (int j = 0; j < 6; ++j) {
            const float* rp = &buf[(r0 + j) * 128];
            float4 q = *(const float4*)&rp[oc0];
            float lv = rp[lcl];
            float rv = rp[rcl];
            rl[j]  = (mc == 0)  ? 0.f : lv;        // x col oc0-1 (or pad 0)
            rrr[j] = (mc == 31) ? 0.f : rv;        // x col oc0+4 (or pad 0)
            rc[j][0] = q.x; rc[j][1] = q.y; rc[j][2] = q.z; rc[j][3] = q.w;
        }
        float* po = out + (size_t)plane * HW_;
        #pragma unroll
        for (int rr = 0; rr < 4; ++rr) {
            float res[4];
            #pragma unroll
            for (int cc = 0; cc < 4; ++cc) {
                float s = 0.f;
                #pragma unroll
                for (int dy = 0; dy < 3; ++dy) {
                    #pragma unroll
                    for (int dx = 0; dx < 3; ++dx) {
                        int col = cc + dx - 1;              // compile-time
                        float vv = (col < 0) ? rl[rr + dy]
                                 : (col > 3) ? rrr[rr + dy]
                                 : rc[rr + dy][col];
                        s += w[dy * 3 + dx] * vv;
                    }
                }
                res[cc] = s;
            }
            nfloat4 rv = { res[0], res[1], res[2], res[3] };
            __builtin_nontemporal_store(rv,
                (nfloat4*)&po[(r0 + rr) * W_ + oc0]);
        }
        if (g < PPB - 1) {
            __syncthreads();               // all reads of buf done block-wide
            #pragma unroll
            for (int i = 0; i < 4; ++i)    // write plane g+1 (linear b128)
                *(float4*)&buf[128 + ((i * 1024 + t) << 2)] = pre[i];
            __syncthreads();
            if (g < PPB - 2) {             // issue plane g+2 loads early
                const float* xn = x + (size_t)(plane + 2) * HW_;
                #pragma unroll
                for (int i = 0; i < 4; ++i)
                    pre[i] = *(const float4*)&xn[(i * 1024 + t) << 2];
            }
        }
    }
}

extern "C" void kernel_launch(void* const* d_in, const int* in_sizes, int n_in,
                              void* d_out, int out_size, void* d_ws, size_t ws_size,
                              hipStream_t stream) {
    const float* x     = (const float*)d_in[0];
    const float* wconv = (const float*)d_in[1];
    const float* gamma = (const float*)d_in[2];
    const float* beta  = (const float*)d_in[3];
    float* out = (float*)d_out;

    float* xpT = (float*)d_ws;                   // C*N*256 = 262144 floats
    float* w9  = xpT + C_ * N_ * 256;            // N*256*OC = 9216 floats
    unsigned* bar = (unsigned*)(w9 + N_ * 256 * OC);   // 2 counters

    hipMemsetAsync(bar, 0, 2 * sizeof(unsigned), stream);  // ws is poisoned
    hipLaunchKernelGGL(fused_kernel, dim3(NBLK), dim3(1024), 0, stream,
                       x, wconv, gamma, beta, xpT, w9, out, bar);
}